// Round 5
// baseline (114.266 us; speedup 1.0000x reference)
//
#include <hip/hip_runtime.h>

// Conv2d 3x3 s1 p1 NCHW fp32: N=32, Cin=128, H=W=56, Cout=256.
// Round 5: 256x256 tile, 8-wave, BK=32, counted-vmcnt pipeline (T4).
//   A = weights [tap][co][ci] bf16 (wT), B = im2col from padded xTp.
//   LDS: 2 slots x (A 16KB + B 16KB) = 64KB static. 1 block/CU, 2 waves/SIMD.
//   Packing: 2 rows (co or m) per 128B LDS row; chunk ^= (ldsrow&7) swizzle
//   (same family as rounds 2-4, measured 0 bank conflicts).
//   Per K-tile: STAGE(t+1); vmcnt(4); s_barrier; 12 ds_read_b128 + 32 MFMA;
//   s_barrier.  vmcnt never drained to 0 in the main loop (T4).

typedef __attribute__((ext_vector_type(8))) short short8;
typedef __attribute__((ext_vector_type(4))) float float4v;

constexpr int NB = 32, CI = 128, HH = 56, WW = 56, CO = 256;
constexpr int HWP = HH * WW;                 // 3136
constexpr int HP = 58, WP = 58;              // padded spatial dims
constexpr size_t XTP_BYTES = (size_t)NB * HP * WP * CI * 2;   // 27,553,792
constexpr size_t WT_OFF    = XTP_BYTES;
constexpr size_t WT_BYTES  = (size_t)9 * CO * CI * 2;         // 589,824
constexpr size_t WS_NEED   = WT_OFF + WT_BYTES;

__device__ inline ushort f2bf(float v) {
    union { float f; uint u; } c; c.f = v;
    uint u = c.u;
    return (ushort)((u + 0x7fffu + ((u >> 16) & 1u)) >> 16);
}

// ---- x: [n][ci][h][w] f32 -> xTp interior: [n][h+1][w+1][ci] bf16 ----
__global__ __launch_bounds__(256) void xform_x(const float* __restrict__ x,
                                               ushort* __restrict__ xTp) {
    int b = blockIdx.x;
    int cit = b & 3;
    int hwt = (b >> 2) % 49;
    int n   = b / (4 * 49);
    int ci0 = cit * 32, hw0 = hwt * 64;
    __shared__ float t[32][65];
    int tx = threadIdx.x;
    int col = tx & 63, r4 = tx >> 6;
#pragma unroll
    for (int rr = 0; rr < 8; ++rr) {
        int row = rr * 4 + r4;
        t[row][col] = x[((size_t)n * CI + ci0 + row) * HWP + hw0 + col];
    }
    __syncthreads();
    int i = tx & 31, j0 = tx >> 5;
#pragma unroll
    for (int jj = 0; jj < 8; ++jj) {
        int j = jj * 8 + j0;
        int hw = hw0 + j;
        int h = hw / WW, w = hw % WW;
        xTp[(((size_t)n * HP + h + 1) * WP + (w + 1)) * CI + ci0 + i] = f2bf(t[i][j]);
    }
}

// ---- zero-fill padded borders ----
__global__ __launch_bounds__(256) void xform_border(ushort* __restrict__ xTp) {
    int u = blockIdx.x * 256 + threadIdx.x;   // 116736 units of short8
    int ci8 = u & 15;
    int r = u >> 4;
    int n = r / 228, bb = r % 228;
    int hp, wp;
    if (bb < 58)       { hp = 0;  wp = bb; }
    else if (bb < 116) { hp = 57; wp = bb - 58; }
    else { int c = bb - 116; hp = 1 + (c >> 1); wp = (c & 1) * 57; }
    short8 z = (short8)0;
    *reinterpret_cast<short8*>(xTp + (((size_t)n * HP + hp) * WP + wp) * CI + ci8 * 8) = z;
}

// ---- w: [co][ci][kh][kw] f32 -> wT: [tap][co][ci] bf16 ----
__global__ __launch_bounds__(256) void xform_w(const float* __restrict__ w,
                                               ushort* __restrict__ wT) {
    int o = blockIdx.x * 256 + threadIdx.x;
    int ci = o & 127;
    int co = (o >> 7) & 255;
    int tap = o >> 15;
    wT[o] = f2bf(w[((size_t)co * CI + ci) * 9 + tap]);
}

// ---- main implicit GEMM: 256x256 tile, 8 waves, BK=32, counted vmcnt ----
__global__ __launch_bounds__(512, 2) void gemm_conv(
    const ushort* __restrict__ xTp, const ushort* __restrict__ wT,
    const float* __restrict__ bias, float* __restrict__ out)
{
    // slot layout: [slot][128 lds-rows][64 ushort] ; 2 tile-rows per lds-row
    __shared__ ushort As[2][128 * 64];   // 16KB x2  (weights: 256 co x 32 k)
    __shared__ ushort Bs[2][128 * 64];   // 16KB x2  (im2col : 256 m  x 32 k)

    // XCD swizzle: 392 = 8 x 49, bijective
    int b = blockIdx.x;
    const int mblk = (b & 7) * 49 + (b >> 3);

    const int tid = threadIdx.x, lane = tid & 63, wv = tid >> 6;  // 8 waves
    const int wr = wv >> 2;          // co-half   (0..1) -> 128 co rows
    const int wc = wv & 3;           // m-quarter (0..3) -> 64 m cols
    const int s = (lane & 7) ^ ((lane >> 3) & 7);   // pre-swizzled src chunk

    // ---- staging offsets (2 loads/thread per operand per tile) ----
    // load q: lds-row r = wv*16 + q*8 + (lane>>3); dest chunk = lane&7,
    // holds natural chunk s = (lane&7)^(r&7); tile-row = 2r + (s>>2),
    // k-chunk = s&3.
    int aBase[2], bBase[2];
#pragma unroll
    for (int q = 0; q < 2; ++q) {
        int r = wv * 16 + q * 8 + (lane >> 3);
        int row2 = 2 * r + (s >> 2);          // co (A) or m-local (B)
        aBase[q] = row2 * CI + (s & 3) * 8;
        int m = mblk * 256 + row2;
        int n = m / HWP, hw = m % HWP, h = hw / WW, w = hw % WW;
        bBase[q] = ((n * HP + h + 1) * WP + (w + 1)) * CI + (s & 3) * 8;
    }

    float4v acc[8][4];
#pragma unroll
    for (int i = 0; i < 8; ++i)
#pragma unroll
        for (int j = 0; j < 4; ++j) acc[i][j] = (float4v)(0.0f);

    // K-tile t (0..35): tap = t>>2, qk = t&3 (k-quarter of 128 ci)
    auto STAGE = [&](int slot, int t) {
        int tap = t >> 2, qk = t & 3;
        int dh = tap / 3 - 1, dw = tap % 3 - 1;
        int ao = tap * (CO * CI) + qk * 32;
        int bo = (dh * WP + dw) * CI + qk * 32;
        ushort* asb = &As[slot][0];
        ushort* bsb = &Bs[slot][0];
#pragma unroll
        for (int q = 0; q < 2; ++q)
            __builtin_amdgcn_global_load_lds(
                (const __attribute__((address_space(1))) uint*)(wT + aBase[q] + ao),
                (__attribute__((address_space(3))) uint*)(asb + (wv * 16 + q * 8) * 64),
                16, 0, 0);
#pragma unroll
        for (int q = 0; q < 2; ++q)
            __builtin_amdgcn_global_load_lds(
                (const __attribute__((address_space(1))) uint*)(xTp + bBase[q] + bo),
                (__attribute__((address_space(3))) uint*)(bsb + (wv * 16 + q * 8) * 64),
                16, 0, 0);
    };

    // prologue: tile 0 -> slot 0  (4 loads/thread in flight)
    STAGE(0, 0);

#pragma unroll 1
    for (int t = 0; t < 36; ++t) {
        const int sl = t & 1;
        if (t < 35) {
            STAGE(sl ^ 1, t + 1);   // 4 more loads -> 8 outstanding
            asm volatile("s_waitcnt vmcnt(4)" ::: "memory");  // drain tile t's 4
        } else {
            asm volatile("s_waitcnt vmcnt(0)" ::: "memory");
        }
        __builtin_amdgcn_s_barrier();        // collective: tile t fully in LDS
        asm volatile("" ::: "memory");

        // fragment reads: a[8] (128 co rows), b[4] (64 m cols), k=32
        const ushort* asb = &As[sl][0];
        const ushort* bsb = &Bs[sl][0];
        short8 a[8], bf[4];
#pragma unroll
        for (int f = 0; f < 8; ++f) {
            int co = wr * 128 + f * 16 + (lane & 15);
            int r = co >> 1;
            int ch = (((co & 1) * 4 + (lane >> 4))) ^ (r & 7);
            a[f] = *(const short8*)(asb + r * 64 + ch * 8);
        }
#pragma unroll
        for (int g = 0; g < 4; ++g) {
            int mr = wc * 64 + g * 16 + (lane & 15);
            int r = mr >> 1;
            int ch = (((mr & 1) * 4 + (lane >> 4))) ^ (r & 7);
            bf[g] = *(const short8*)(bsb + r * 64 + ch * 8);
        }

        __builtin_amdgcn_s_setprio(1);
#pragma unroll
        for (int f = 0; f < 8; ++f)
#pragma unroll
            for (int g = 0; g < 4; ++g)
                acc[f][g] = __builtin_amdgcn_mfma_f32_16x16x32_bf16(
                    a[f], bf[g], acc[f][g], 0, 0, 0);
        __builtin_amdgcn_s_setprio(0);

        asm volatile("" ::: "memory");
        __builtin_amdgcn_s_barrier();        // all reads of slot sl retired
        asm volatile("" ::: "memory");
    }

    // epilogue: C[co][m] + bias -> out[n][co][h][w]
    const int co0 = wr * 128;
    const int m0  = mblk * 256 + wc * 64;
    float bv[8][4];
#pragma unroll
    for (int f = 0; f < 8; ++f)
#pragma unroll
        for (int r = 0; r < 4; ++r)
            bv[f][r] = bias[co0 + f * 16 + (lane >> 4) * 4 + r];
#pragma unroll
    for (int g = 0; g < 4; ++g) {
        int m = m0 + g * 16 + (lane & 15);
        int n = m / HWP, hw = m % HWP;
        float* obase = out + (size_t)n * CO * HWP + hw;
#pragma unroll
        for (int f = 0; f < 8; ++f) {
            int co = co0 + f * 16 + (lane >> 4) * 4;
#pragma unroll
            for (int r = 0; r < 4; ++r)
                obase[(size_t)(co + r) * HWP] = acc[f][g][r] + bv[f][r];
        }
    }
}

// ---- fallback (round-1 direct conv) if ws too small ----
__global__ __launch_bounds__(256) void conv_k(
    const float* __restrict__ x, const float* __restrict__ wgt,
    const float* __restrict__ bias, float* __restrict__ out)
{
    int idx = blockIdx.x * 256 + threadIdx.x;
    int wg = idx % 14; int t = idx / 14;
    int ho = t % 56; t /= 56;
    int cog = t % 64; int n = t / 64;
    int w0 = wg * 4, co0 = cog * 4;
    float acc[4][4];
#pragma unroll
    for (int j = 0; j < 4; ++j) {
        float bj = bias[co0 + j];
#pragma unroll
        for (int p = 0; p < 4; ++p) acc[j][p] = bj;
    }
    const float* xn = x + (size_t)n * CI * HWP;
    for (int ci = 0; ci < CI; ++ci) {
        float xr[3][6];
#pragma unroll
        for (int kh = 0; kh < 3; ++kh) {
            int hi = ho + kh - 1;
            if (hi >= 0 && hi < HH) {
                const float* row = xn + ((size_t)ci * HH + hi) * WW;
                float4 c = *reinterpret_cast<const float4*>(row + w0);
                xr[kh][1] = c.x; xr[kh][2] = c.y; xr[kh][3] = c.z; xr[kh][4] = c.w;
                xr[kh][0] = (w0 > 0) ? row[w0 - 1] : 0.0f;
                xr[kh][5] = (w0 + 4 < WW) ? row[w0 + 4] : 0.0f;
            } else {
#pragma unroll
                for (int q = 0; q < 6; ++q) xr[kh][q] = 0.0f;
            }
        }
#pragma unroll
        for (int j = 0; j < 4; ++j) {
            const float* wp = wgt + ((size_t)(co0 + j) * CI + ci) * 9;
            float wvv[9];
#pragma unroll
            for (int q = 0; q < 9; ++q) wvv[q] = wp[q];
#pragma unroll
            for (int kh = 0; kh < 3; ++kh)
#pragma unroll
                for (int kw = 0; kw < 3; ++kw)
#pragma unroll
                    for (int p = 0; p < 4; ++p)
                        acc[j][p] = fmaf(xr[kh][p + kw], wvv[kh * 3 + kw], acc[j][p]);
        }
    }
#pragma unroll
    for (int j = 0; j < 4; ++j) {
        float4 v = make_float4(acc[j][0], acc[j][1], acc[j][2], acc[j][3]);
        *reinterpret_cast<float4*>(out + (((size_t)n * CO + co0 + j) * HH + ho) * WW + w0) = v;
    }
}

extern "C" void kernel_launch(void* const* d_in, const int* in_sizes, int n_in,
                              void* d_out, int out_size, void* d_ws, size_t ws_size,
                              hipStream_t stream) {
    const float* x = (const float*)d_in[0];
    const float* w = (const float*)d_in[1];
    const float* b = (const float*)d_in[2];
    float* out = (float*)d_out;

    if (ws_size < WS_NEED) {  // safety fallback
        hipLaunchKernelGGL(conv_k, dim3(6272), dim3(256), 0, stream, x, w, b, out);
        return;
    }

    ushort* xTp = (ushort*)d_ws;
    ushort* wT  = (ushort*)((char*)d_ws + WT_OFF);

    hipLaunchKernelGGL(xform_x, dim3(32 * 49 * 4), dim3(256), 0, stream, x, xTp);
    hipLaunchKernelGGL(xform_border, dim3(456), dim3(256), 0, stream, xTp);
    hipLaunchKernelGGL(xform_w, dim3(9 * CO * CI / 256), dim3(256), 0, stream, w, wT);
    hipLaunchKernelGGL(gemm_conv, dim3(392), dim3(512), 0, stream,
                       xTp, wT, b, out);
}

// Round 6
// 103.316 us; speedup vs baseline: 1.1060x; 1.1060x over previous
//
#include <hip/hip_runtime.h>

// Conv2d 3x3 s1 p1 NCHW fp32: N=32, Cin=128, H=W=56, Cout=256.
// Round 6: full 8-phase 256x256 template (m201 port).
//   A = wT [tap][co][ci] bf16, B = im2col from padded xTp [n][58][58][ci] bf16.
//   BM=BN=256, BK=64, 18 K-tiles (9 taps x 2 ci-halves), 8 waves (512 thr),
//   wave-tile 128(co) x 64(m). LDS 128KB: As[2][256][64] + Bs[2][256][64].
//   Per K-tile 4 phases: {ds-read quadrant frags + issue 1 half-tile stage;
//   s_barrier; setprio(1); 16 MFMA; setprio(0); s_barrier}. Quadrants
//   (qr,qc) = (0,0),(0,1),(1,1),(1,0): B-qc0 register-held for ph4.
//   Staging stagger (tile u's halves): B-h0 @ (u-2).ph3, A-h0 @ (u-2).ph4,
//   A-h1 @ (u-1).ph1, B-h1 @ (u-1).ph2.  Hazards: each write targets a
//   region whose last LDS reads retired >=1 barrier earlier (see derivation).
//   vmcnt(4) once per tile (ph4 closing barrier); vmcnt(0) only in tail.
//   XOR chunk swizzle (^row&7) on stage-source + frag reads (0 conflicts,
//   verified R2-R5).

typedef __attribute__((ext_vector_type(8))) short short8;
typedef __attribute__((ext_vector_type(4))) float float4v;

constexpr int NB = 32, CI = 128, HH = 56, WW = 56, CO = 256;
constexpr int HWP = HH * WW;                 // 3136
constexpr int HP = 58, WP = 58;              // padded spatial dims
constexpr size_t XTP_BYTES = (size_t)NB * HP * WP * CI * 2;   // 27,553,792
constexpr size_t WT_OFF    = XTP_BYTES;
constexpr size_t WT_BYTES  = (size_t)9 * CO * CI * 2;         // 589,824
constexpr size_t WS_NEED   = WT_OFF + WT_BYTES;

__device__ inline ushort f2bf(float v) {
    union { float f; uint u; } c; c.f = v;
    uint u = c.u;
    return (ushort)((u + 0x7fffu + ((u >> 16) & 1u)) >> 16);
}

__device__ inline void gll(const ushort* g, ushort* l) {
    __builtin_amdgcn_global_load_lds(
        (const __attribute__((address_space(1))) uint*)g,
        (__attribute__((address_space(3))) uint*)l, 16, 0, 0);
}

#define BAR() do { asm volatile("" ::: "memory"); \
                   __builtin_amdgcn_s_barrier(); \
                   asm volatile("" ::: "memory"); } while (0)

// ---- x: [n][ci][h][w] f32 -> xTp interior: [n][h+1][w+1][ci] bf16 ----
__global__ __launch_bounds__(256) void xform_x(const float* __restrict__ x,
                                               ushort* __restrict__ xTp) {
    int b = blockIdx.x;
    int cit = b & 3;
    int hwt = (b >> 2) % 49;
    int n   = b / (4 * 49);
    int ci0 = cit * 32, hw0 = hwt * 64;
    __shared__ float t[32][65];
    int tx = threadIdx.x;
    int col = tx & 63, r4 = tx >> 6;
#pragma unroll
    for (int rr = 0; rr < 8; ++rr) {
        int row = rr * 4 + r4;
        t[row][col] = x[((size_t)n * CI + ci0 + row) * HWP + hw0 + col];
    }
    __syncthreads();
    int i = tx & 31, j0 = tx >> 5;
#pragma unroll
    for (int jj = 0; jj < 8; ++jj) {
        int j = jj * 8 + j0;
        int hw = hw0 + j;
        int h = hw / WW, w = hw % WW;
        xTp[(((size_t)n * HP + h + 1) * WP + (w + 1)) * CI + ci0 + i] = f2bf(t[i][j]);
    }
}

// ---- zero-fill padded borders ----
__global__ __launch_bounds__(256) void xform_border(ushort* __restrict__ xTp) {
    int u = blockIdx.x * 256 + threadIdx.x;   // 116736 units of short8
    int ci8 = u & 15;
    int r = u >> 4;
    int n = r / 228, bb = r % 228;
    int hp, wp;
    if (bb < 58)       { hp = 0;  wp = bb; }
    else if (bb < 116) { hp = 57; wp = bb - 58; }
    else { int c = bb - 116; hp = 1 + (c >> 1); wp = (c & 1) * 57; }
    short8 z = (short8)0;
    *reinterpret_cast<short8*>(xTp + (((size_t)n * HP + hp) * WP + wp) * CI + ci8 * 8) = z;
}

// ---- w: [co][ci][kh][kw] f32 -> wT: [tap][co][ci] bf16 ----
__global__ __launch_bounds__(256) void xform_w(const float* __restrict__ w,
                                               ushort* __restrict__ wT) {
    int o = blockIdx.x * 256 + threadIdx.x;
    int ci = o & 127;
    int co = (o >> 7) & 255;
    int tap = o >> 15;
    wT[o] = f2bf(w[((size_t)co * CI + ci) * 9 + tap]);
}

// ---- main implicit GEMM: 256x256 tile, 8-phase schedule ----
__global__ __launch_bounds__(512, 2) void gemm_conv(
    const ushort* __restrict__ xTp, const ushort* __restrict__ wT,
    const float* __restrict__ bias, float* __restrict__ out)
{
    __shared__ ushort As[2][256 * 64];   // 32KB x2 (weights: co x k)
    __shared__ ushort Bs[2][256 * 64];   // 32KB x2 (im2col : m  x k)

    // XCD swizzle: 392 = 8 x 49, bijective
    int b = blockIdx.x;
    const int mblk = (b & 7) * 49 + (b >> 3);

    const int tid = threadIdx.x, lane = tid & 63, wv = tid >> 6;  // 8 waves
    const int wr = wv >> 2;          // co-half  (0..1) -> 128 co rows
    const int wc = wv & 3;           // m-quarter(0..3) -> 64 m cols

    // ---- staging addressing (half-tile = 128 rows x 64 k = 16KB; 2 loads/thr)
    // row = h*128 + q*64 + (tid>>3); dest chunk = tid&7;
    // src chunk = (tid&7) ^ (row&7), row&7 = (tid>>3)&7.
    const int s8 = (((tid & 7) ^ ((tid >> 3) & 7))) * 8;   // src chunk elems
    const int aSrc = (tid >> 3) * CI + s8;                  // + tap*32768 + kh + h*16384 + q*8192
    const int dstOff = (tid >> 3) * 64 + (tid & 7) * 8;     // + h*8192 + q*4096 (ushorts)

    int bPix[4];  // [h*2+q]: pixel base offset incl. s8
#pragma unroll
    for (int hq = 0; hq < 4; ++hq) {
        int m = mblk * 256 + (hq >> 1) * 128 + (hq & 1) * 64 + (tid >> 3);
        int n = m / HWP, hw = m % HWP, h = hw / WW, w = hw % WW;
        bPix[hq] = ((n * HP + h + 1) * WP + (w + 1)) * CI + s8;
    }

    // ---- fragment-read addressing (verified R2-R5):
    // row = base + f*16 + (lane&15); chunk(kc) = (kc*4 + (lane>>4)) ^ (lane&7)
    const int ck0 = (((lane >> 4)) ^ (lane & 7)) * 8;
    const int ck1 = ((4 + (lane >> 4)) ^ (lane & 7)) * 8;
    const int aRowOff = (wr * 128 + (lane & 15)) * 64;      // + qr*4096 + fi*1024
    const int bRowOff = (wc * 64 + (lane & 15)) * 64;       // + qc*2048 + gi*1024

    float4v acc[8][4];
#pragma unroll
    for (int i = 0; i < 8; ++i)
#pragma unroll
        for (int j = 0; j < 4; ++j) acc[i][j] = (float4v)(0.0f);

    short8 aF[4][2];      // current qr-half A frags
    short8 bQ0[2][2];     // B qc0 frags (held ph1..ph4)
    short8 bQ1[2][2];     // B qc1 frags (held ph2..ph3)

    auto STAGE_A = [&](int buf, int t, int h) {
        int tap = t >> 1, kh = (t & 1) * 64;
        const ushort* src = wT + aSrc + tap * (CO * CI) + kh + h * 16384;
        ushort* dst = &As[buf][h * 8192 + dstOff];
        gll(src, dst);
        gll(src + 8192, dst + 4096);
    };
    auto STAGE_B = [&](int buf, int t, int h) {
        int tap = t >> 1, kh = (t & 1) * 64;
        int dh = tap / 3 - 1, dw = tap % 3 - 1;
        int toff = (dh * WP + dw) * CI + kh;
        ushort* dst = &Bs[buf][h * 8192 + dstOff];
        gll(xTp + bPix[h * 2 + 0] + toff, dst);
        gll(xTp + bPix[h * 2 + 1] + toff, dst + 4096);
    };
    auto LDA = [&](int buf, int qr) {
        const ushort* p = &As[buf][aRowOff + qr * 4096];
#pragma unroll
        for (int fi = 0; fi < 4; ++fi) {
            aF[fi][0] = *(const short8*)(p + fi * 1024 + ck0);
            aF[fi][1] = *(const short8*)(p + fi * 1024 + ck1);
        }
    };
    auto LDB = [&](int buf, int qc, short8 (&bF)[2][2]) {
        const ushort* p = &Bs[buf][bRowOff + qc * 2048];
#pragma unroll
        for (int gi = 0; gi < 2; ++gi) {
            bF[gi][0] = *(const short8*)(p + gi * 1024 + ck0);
            bF[gi][1] = *(const short8*)(p + gi * 1024 + ck1);
        }
    };

#define MMQ(QR, QC, BF) do { \
    __builtin_amdgcn_s_setprio(1); \
    _Pragma("unroll") \
    for (int fi = 0; fi < 4; ++fi) \
        _Pragma("unroll") \
        for (int gi = 0; gi < 2; ++gi) \
            _Pragma("unroll") \
            for (int kc = 0; kc < 2; ++kc) \
                acc[(QR)*4+fi][(QC)*2+gi] = __builtin_amdgcn_mfma_f32_16x16x32_bf16( \
                    aF[fi][kc], (BF)[gi][kc], acc[(QR)*4+fi][(QC)*2+gi], 0, 0, 0); \
    __builtin_amdgcn_s_setprio(0); \
} while (0)

    // ---- prologue: tile0 (4 halves) + B-h0(1), A-h0(1)  [steady-state image]
    STAGE_A(0, 0, 0); STAGE_A(0, 0, 1);
    STAGE_B(0, 0, 0); STAGE_B(0, 0, 1);
    STAGE_B(1, 1, 0); STAGE_A(1, 1, 0);
    asm volatile("s_waitcnt vmcnt(4)" ::: "memory");   // tile0 landed, 2 halves fly
    BAR();

#pragma unroll 1
    for (int t = 0; t < 18; ++t) {
        const int c = t & 1;
        // ph1: read A-qr0 + B-qc0 ; stage A-h1(t+1) -> buf c^1
        LDA(c, 0);
        LDB(c, 0, bQ0);
        if (t + 1 < 18) STAGE_A(c ^ 1, t + 1, 1);
        BAR();
        MMQ(0, 0, bQ0);
        BAR();
        // ph2: read B-qc1 ; stage B-h1(t+1) -> buf c^1
        LDB(c, 1, bQ1);
        if (t + 1 < 18) STAGE_B(c ^ 1, t + 1, 1);
        BAR();
        MMQ(0, 1, bQ1);
        BAR();
        // ph3: read A-qr1 ; stage B-h0(t+2) -> buf c (B reads of t done @ph2)
        LDA(c, 1);
        if (t + 2 < 18) STAGE_B(c, t + 2, 0);
        BAR();
        MMQ(1, 1, bQ1);
        BAR();
        // ph4: no reads ; stage A-h0(t+2) -> buf c (A reads of t done @ph3)
        if (t + 2 < 18) STAGE_A(c, t + 2, 0);
        BAR();
        MMQ(1, 0, bQ0);
        // boundary guard for next tile's ph1 reads (once per tile, counted)
        if (t < 16) { asm volatile("s_waitcnt vmcnt(4)" ::: "memory"); }
        else        { asm volatile("s_waitcnt vmcnt(0)" ::: "memory"); }
        BAR();
    }
#undef MMQ

    // ---- epilogue: C[co][m] + bias -> out[n][co][h][w]  (verified R5 layout)
    const int co0 = wr * 128;
    const int m0  = mblk * 256 + wc * 64;
    float bv[8][4];
#pragma unroll
    for (int f = 0; f < 8; ++f)
#pragma unroll
        for (int r = 0; r < 4; ++r)
            bv[f][r] = bias[co0 + f * 16 + (lane >> 4) * 4 + r];
#pragma unroll
    for (int g = 0; g < 4; ++g) {
        int m = m0 + g * 16 + (lane & 15);
        int n = m / HWP, hw = m % HWP;
        float* obase = out + (size_t)n * CO * HWP + hw;
#pragma unroll
        for (int f = 0; f < 8; ++f) {
            int co = co0 + f * 16 + (lane >> 4) * 4;
#pragma unroll
            for (int r = 0; r < 4; ++r)
                obase[(size_t)(co + r) * HWP] = acc[f][g][r] + bv[f][r];
        }
    }
}

// ---- fallback (round-1 direct conv) if ws too small ----
__global__ __launch_bounds__(256) void conv_k(
    const float* __restrict__ x, const float* __restrict__ wgt,
    const float* __restrict__ bias, float* __restrict__ out)
{
    int idx = blockIdx.x * 256 + threadIdx.x;
    int wg = idx % 14; int t = idx / 14;
    int ho = t % 56; t /= 56;
    int cog = t % 64; int n = t / 64;
    int w0 = wg * 4, co0 = cog * 4;
    float acc[4][4];
#pragma unroll
    for (int j = 0; j < 4; ++j) {
        float bj = bias[co0 + j];
#pragma unroll
        for (int p = 0; p < 4; ++p) acc[j][p] = bj;
    }
    const float* xn = x + (size_t)n * CI * HWP;
    for (int ci = 0; ci < CI; ++ci) {
        float xr[3][6];
#pragma unroll
        for (int kh = 0; kh < 3; ++kh) {
            int hi = ho + kh - 1;
            if (hi >= 0 && hi < HH) {
                const float* row = xn + ((size_t)ci * HH + hi) * WW;
                float4 cc = *reinterpret_cast<const float4*>(row + w0);
                xr[kh][1] = cc.x; xr[kh][2] = cc.y; xr[kh][3] = cc.z; xr[kh][4] = cc.w;
                xr[kh][0] = (w0 > 0) ? row[w0 - 1] : 0.0f;
                xr[kh][5] = (w0 + 4 < WW) ? row[w0 + 4] : 0.0f;
            } else {
#pragma unroll
                for (int q = 0; q < 6; ++q) xr[kh][q] = 0.0f;
            }
        }
#pragma unroll
        for (int j = 0; j < 4; ++j) {
            const float* wp = wgt + ((size_t)(co0 + j) * CI + ci) * 9;
            float wvv[9];
#pragma unroll
            for (int q = 0; q < 9; ++q) wvv[q] = wp[q];
#pragma unroll
            for (int kh = 0; kh < 3; ++kh)
#pragma unroll
                for (int kw = 0; kw < 3; ++kw)
#pragma unroll
                    for (int p = 0; p < 4; ++p)
                        acc[j][p] = fmaf(xr[kh][p + kw], wvv[kh * 3 + kw], acc[j][p]);
        }
    }
#pragma unroll
    for (int j = 0; j < 4; ++j) {
        float4 v = make_float4(acc[j][0], acc[j][1], acc[j][2], acc[j][3]);
        *reinterpret_cast<float4*>(out + (((size_t)n * CO + co0 + j) * HH + ho) * WW + w0) = v;
    }
}

extern "C" void kernel_launch(void* const* d_in, const int* in_sizes, int n_in,
                              void* d_out, int out_size, void* d_ws, size_t ws_size,
                              hipStream_t stream) {
    const float* x = (const float*)d_in[0];
    const float* w = (const float*)d_in[1];
    const float* b = (const float*)d_in[2];
    float* out = (float*)d_out;

    if (ws_size < WS_NEED) {  // safety fallback
        hipLaunchKernelGGL(conv_k, dim3(6272), dim3(256), 0, stream, x, w, b, out);
        return;
    }

    ushort* xTp = (ushort*)d_ws;
    ushort* wT  = (ushort*)((char*)d_ws + WT_OFF);

    hipLaunchKernelGGL(xform_x, dim3(32 * 49 * 4), dim3(256), 0, stream, x, xTp);
    hipLaunchKernelGGL(xform_border, dim3(456), dim3(256), 0, stream, xTp);
    hipLaunchKernelGGL(xform_w, dim3(9 * CO * CI / 256), dim3(256), 0, stream, w, wT);
    hipLaunchKernelGGL(gemm_conv, dim3(392), dim3(512), 0, stream,
                       xTp, wT, b, out);
}

// Round 7
// 95.819 us; speedup vs baseline: 1.1925x; 1.0782x over previous
//
#include <hip/hip_runtime.h>

// Conv2d 3x3 s1 p1 NCHW fp32: N=32, Cin=128, H=W=56, Cout=256.
// Round 7: 8-phase 256x256 (R6) with 1 barrier/phase (5/tile, was 8),
//   kc-outer MFMA order (independent 8-runs), K-loop unrolled x2 (static
//   buffer parity). Stagger/vmcnt identical to R6 (hazard distances >=1
//   barrier + ~200cy gll latency vs ~120cy ds_read completion).

typedef __attribute__((ext_vector_type(8))) short short8;
typedef __attribute__((ext_vector_type(4))) float float4v;

constexpr int NB = 32, CI = 128, HH = 56, WW = 56, CO = 256;
constexpr int HWP = HH * WW;                 // 3136
constexpr int HP = 58, WP = 58;              // padded spatial dims
constexpr size_t XTP_BYTES = (size_t)NB * HP * WP * CI * 2;   // 27,553,792
constexpr size_t WT_OFF    = XTP_BYTES;
constexpr size_t WT_BYTES  = (size_t)9 * CO * CI * 2;         // 589,824
constexpr size_t WS_NEED   = WT_OFF + WT_BYTES;

__device__ inline ushort f2bf(float v) {
    union { float f; uint u; } c; c.f = v;
    uint u = c.u;
    return (ushort)((u + 0x7fffu + ((u >> 16) & 1u)) >> 16);
}

__device__ inline void gll(const ushort* g, ushort* l) {
    __builtin_amdgcn_global_load_lds(
        (const __attribute__((address_space(1))) uint*)g,
        (__attribute__((address_space(3))) uint*)l, 16, 0, 0);
}

#define BAR() do { asm volatile("" ::: "memory"); \
                   __builtin_amdgcn_s_barrier(); \
                   asm volatile("" ::: "memory"); } while (0)

// ---- x: [n][ci][h][w] f32 -> xTp interior: [n][h+1][w+1][ci] bf16 ----
__global__ __launch_bounds__(256) void xform_x(const float* __restrict__ x,
                                               ushort* __restrict__ xTp) {
    int b = blockIdx.x;
    int cit = b & 3;
    int hwt = (b >> 2) % 49;
    int n   = b / (4 * 49);
    int ci0 = cit * 32, hw0 = hwt * 64;
    __shared__ float t[32][65];
    int tx = threadIdx.x;
    int col = tx & 63, r4 = tx >> 6;
#pragma unroll
    for (int rr = 0; rr < 8; ++rr) {
        int row = rr * 4 + r4;
        t[row][col] = x[((size_t)n * CI + ci0 + row) * HWP + hw0 + col];
    }
    __syncthreads();
    int i = tx & 31, j0 = tx >> 5;
#pragma unroll
    for (int jj = 0; jj < 8; ++jj) {
        int j = jj * 8 + j0;
        int hw = hw0 + j;
        int h = hw / WW, w = hw % WW;
        xTp[(((size_t)n * HP + h + 1) * WP + (w + 1)) * CI + ci0 + i] = f2bf(t[i][j]);
    }
}

// ---- zero-fill padded borders ----
__global__ __launch_bounds__(256) void xform_border(ushort* __restrict__ xTp) {
    int u = blockIdx.x * 256 + threadIdx.x;   // 116736 units of short8
    int ci8 = u & 15;
    int r = u >> 4;
    int n = r / 228, bb = r % 228;
    int hp, wp;
    if (bb < 58)       { hp = 0;  wp = bb; }
    else if (bb < 116) { hp = 57; wp = bb - 58; }
    else { int c = bb - 116; hp = 1 + (c >> 1); wp = (c & 1) * 57; }
    short8 z = (short8)0;
    *reinterpret_cast<short8*>(xTp + (((size_t)n * HP + hp) * WP + wp) * CI + ci8 * 8) = z;
}

// ---- w: [co][ci][kh][kw] f32 -> wT: [tap][co][ci] bf16 ----
__global__ __launch_bounds__(256) void xform_w(const float* __restrict__ w,
                                               ushort* __restrict__ wT) {
    int o = blockIdx.x * 256 + threadIdx.x;
    int ci = o & 127;
    int co = (o >> 7) & 255;
    int tap = o >> 15;
    wT[o] = f2bf(w[((size_t)co * CI + ci) * 9 + tap]);
}

// ---- main implicit GEMM: 256x256 tile, 4-phase/tile, 1 barrier/phase ----
__global__ __launch_bounds__(512, 2) void gemm_conv(
    const ushort* __restrict__ xTp, const ushort* __restrict__ wT,
    const float* __restrict__ bias, float* __restrict__ out)
{
    __shared__ ushort As[2][256 * 64];   // 32KB x2 (weights: co x k)
    __shared__ ushort Bs[2][256 * 64];   // 32KB x2 (im2col : m  x k)

    // XCD swizzle: 392 = 8 x 49, bijective
    int b = blockIdx.x;
    const int mblk = (b & 7) * 49 + (b >> 3);

    const int tid = threadIdx.x, lane = tid & 63, wv = tid >> 6;  // 8 waves
    const int wr = wv >> 2;          // co-half  (0..1) -> 128 co rows
    const int wc = wv & 3;           // m-quarter(0..3) -> 64 m cols

    // staging addressing (half-tile = 128 rows x 64 k = 16KB; 2 loads/thr)
    const int s8 = (((tid & 7) ^ ((tid >> 3) & 7))) * 8;   // src chunk elems
    const int aSrc = (tid >> 3) * CI + s8;
    const int dstOff = (tid >> 3) * 64 + (tid & 7) * 8;

    int bPix[4];  // [h*2+q]: pixel base offset incl. s8
#pragma unroll
    for (int hq = 0; hq < 4; ++hq) {
        int m = mblk * 256 + (hq >> 1) * 128 + (hq & 1) * 64 + (tid >> 3);
        int n = m / HWP, hw = m % HWP, h = hw / WW, w = hw % WW;
        bPix[hq] = ((n * HP + h + 1) * WP + (w + 1)) * CI + s8;
    }

    // fragment-read addressing
    const int ck0 = (((lane >> 4)) ^ (lane & 7)) * 8;
    const int ck1 = ((4 + (lane >> 4)) ^ (lane & 7)) * 8;
    const int aRowOff = (wr * 128 + (lane & 15)) * 64;
    const int bRowOff = (wc * 64 + (lane & 15)) * 64;

    float4v acc[8][4];
#pragma unroll
    for (int i = 0; i < 8; ++i)
#pragma unroll
        for (int j = 0; j < 4; ++j) acc[i][j] = (float4v)(0.0f);

    short8 aF[4][2];
    short8 bQ0[2][2];
    short8 bQ1[2][2];

    auto STAGE_A = [&](int buf, int t, int h) {
        int tap = t >> 1, kh = (t & 1) * 64;
        const ushort* src = wT + aSrc + tap * (CO * CI) + kh + h * 16384;
        ushort* dst = &As[buf][h * 8192 + dstOff];
        gll(src, dst);
        gll(src + 8192, dst + 4096);
    };
    auto STAGE_B = [&](int buf, int t, int h) {
        int tap = t >> 1, kh = (t & 1) * 64;
        int dh = tap / 3 - 1, dw = tap % 3 - 1;
        int toff = (dh * WP + dw) * CI + kh;
        ushort* dst = &Bs[buf][h * 8192 + dstOff];
        gll(xTp + bPix[h * 2 + 0] + toff, dst);
        gll(xTp + bPix[h * 2 + 1] + toff, dst + 4096);
    };
    auto LDA = [&](int buf, int qr) {
        const ushort* p = &As[buf][aRowOff + qr * 4096];
#pragma unroll
        for (int fi = 0; fi < 4; ++fi) {
            aF[fi][0] = *(const short8*)(p + fi * 1024 + ck0);
            aF[fi][1] = *(const short8*)(p + fi * 1024 + ck1);
        }
    };
    auto LDB = [&](int buf, int qc, short8 (&bF)[2][2]) {
        const ushort* p = &Bs[buf][bRowOff + qc * 2048];
#pragma unroll
        for (int gi = 0; gi < 2; ++gi) {
            bF[gi][0] = *(const short8*)(p + gi * 1024 + ck0);
            bF[gi][1] = *(const short8*)(p + gi * 1024 + ck1);
        }
    };

// kc-OUTER: two runs of 8 independent MFMAs (no back-to-back dependent pairs)
#define MMQ(QR, QC, BF) do { \
    __builtin_amdgcn_s_setprio(1); \
    _Pragma("unroll") \
    for (int kc = 0; kc < 2; ++kc) \
        _Pragma("unroll") \
        for (int fi = 0; fi < 4; ++fi) \
            _Pragma("unroll") \
            for (int gi = 0; gi < 2; ++gi) \
                acc[(QR)*4+fi][(QC)*2+gi] = __builtin_amdgcn_mfma_f32_16x16x32_bf16( \
                    aF[fi][kc], (BF)[gi][kc], acc[(QR)*4+fi][(QC)*2+gi], 0, 0, 0); \
    __builtin_amdgcn_s_setprio(0); \
} while (0)

    // One K-tile, 4 phases, ONE barrier per phase + boundary vmcnt+BAR.
    auto TILE = [&](int c, int t) {
        // ph1: read A-qr0 + B-qc0 ; stage A-h1(t+1) -> buf c^1
        LDA(c, 0);
        LDB(c, 0, bQ0);
        if (t + 1 < 18) STAGE_A(c ^ 1, t + 1, 1);
        BAR();
        MMQ(0, 0, bQ0);
        // ph2: read B-qc1 ; stage B-h1(t+1) -> buf c^1
        LDB(c, 1, bQ1);
        if (t + 1 < 18) STAGE_B(c ^ 1, t + 1, 1);
        BAR();
        MMQ(0, 1, bQ1);
        // ph3: read A-qr1 ; stage B-h0(t+2) -> buf c
        LDA(c, 1);
        if (t + 2 < 18) STAGE_B(c, t + 2, 0);
        BAR();
        MMQ(1, 1, bQ1);
        // ph4: stage A-h0(t+2) -> buf c
        if (t + 2 < 18) STAGE_A(c, t + 2, 0);
        BAR();
        MMQ(1, 0, bQ0);
        // boundary: tile t+1 fully landed; keep t+2's 4 loads in flight
        if (t <= 15)      { asm volatile("s_waitcnt vmcnt(4)" ::: "memory"); }
        else if (t == 16) { asm volatile("s_waitcnt vmcnt(0)" ::: "memory"); }
        BAR();
    };

    // prologue: tile0 (4 halves) + B-h0(1), A-h0(1)
    STAGE_A(0, 0, 0); STAGE_A(0, 0, 1);
    STAGE_B(0, 0, 0); STAGE_B(0, 0, 1);
    STAGE_B(1, 1, 0); STAGE_A(1, 1, 0);
    asm volatile("s_waitcnt vmcnt(4)" ::: "memory");
    BAR();

#pragma unroll 1
    for (int tp = 0; tp < 18; tp += 2) {   // 9 pairs, static parity
        TILE(0, tp);
        TILE(1, tp + 1);
    }
#undef MMQ

    // epilogue: C[co][m] + bias -> out[n][co][h][w]
    const int co0 = wr * 128;
    const int m0  = mblk * 256 + wc * 64;
    float bv[8][4];
#pragma unroll
    for (int f = 0; f < 8; ++f)
#pragma unroll
        for (int r = 0; r < 4; ++r)
            bv[f][r] = bias[co0 + f * 16 + (lane >> 4) * 4 + r];
#pragma unroll
    for (int g = 0; g < 4; ++g) {
        int m = m0 + g * 16 + (lane & 15);
        int n = m / HWP, hw = m % HWP;
        float* obase = out + (size_t)n * CO * HWP + hw;
#pragma unroll
        for (int f = 0; f < 8; ++f) {
            int co = co0 + f * 16 + (lane >> 4) * 4;
#pragma unroll
            for (int r = 0; r < 4; ++r)
                obase[(size_t)(co + r) * HWP] = acc[f][g][r] + bv[f][r];
        }
    }
}

// ---- fallback (round-1 direct conv) if ws too small ----
__global__ __launch_bounds__(256) void conv_k(
    const float* __restrict__ x, const float* __restrict__ wgt,
    const float* __restrict__ bias, float* __restrict__ out)
{
    int idx = blockIdx.x * 256 + threadIdx.x;
    int wg = idx % 14; int t = idx / 14;
    int ho = t % 56; t /= 56;
    int cog = t % 64; int n = t / 64;
    int w0 = wg * 4, co0 = cog * 4;
    float acc[4][4];
#pragma unroll
    for (int j = 0; j < 4; ++j) {
        float bj = bias[co0 + j];
#pragma unroll
        for (int p = 0; p < 4; ++p) acc[j][p] = bj;
    }
    const float* xn = x + (size_t)n * CI * HWP;
    for (int ci = 0; ci < CI; ++ci) {
        float xr[3][6];
#pragma unroll
        for (int kh = 0; kh < 3; ++kh) {
            int hi = ho + kh - 1;
            if (hi >= 0 && hi < HH) {
                const float* row = xn + ((size_t)ci * HH + hi) * WW;
                float4 cc = *reinterpret_cast<const float4*>(row + w0);
                xr[kh][1] = cc.x; xr[kh][2] = cc.y; xr[kh][3] = cc.z; xr[kh][4] = cc.w;
                xr[kh][0] = (w0 > 0) ? row[w0 - 1] : 0.0f;
                xr[kh][5] = (w0 + 4 < WW) ? row[w0 + 4] : 0.0f;
            } else {
#pragma unroll
                for (int q = 0; q < 6; ++q) xr[kh][q] = 0.0f;
            }
        }
#pragma unroll
        for (int j = 0; j < 4; ++j) {
            const float* wp = wgt + ((size_t)(co0 + j) * CI + ci) * 9;
            float wvv[9];
#pragma unroll
            for (int q = 0; q < 9; ++q) wvv[q] = wp[q];
#pragma unroll
            for (int kh = 0; kh < 3; ++kh)
#pragma unroll
                for (int kw = 0; kw < 3; ++kw)
#pragma unroll
                    for (int p = 0; p < 4; ++p)
                        acc[j][p] = fmaf(xr[kh][p + kw], wvv[kh * 3 + kw], acc[j][p]);
        }
    }
#pragma unroll
    for (int j = 0; j < 4; ++j) {
        float4 v = make_float4(acc[j][0], acc[j][1], acc[j][2], acc[j][3]);
        *reinterpret_cast<float4*>(out + (((size_t)n * CO + co0 + j) * HH + ho) * WW + w0) = v;
    }
}

extern "C" void kernel_launch(void* const* d_in, const int* in_sizes, int n_in,
                              void* d_out, int out_size, void* d_ws, size_t ws_size,
                              hipStream_t stream) {
    const float* x = (const float*)d_in[0];
    const float* w = (const float*)d_in[1];
    const float* b = (const float*)d_in[2];
    float* out = (float*)d_out;

    if (ws_size < WS_NEED) {  // safety fallback
        hipLaunchKernelGGL(conv_k, dim3(6272), dim3(256), 0, stream, x, w, b, out);
        return;
    }

    ushort* xTp = (ushort*)d_ws;
    ushort* wT  = (ushort*)((char*)d_ws + WT_OFF);

    hipLaunchKernelGGL(xform_x, dim3(32 * 49 * 4), dim3(256), 0, stream, x, xTp);
    hipLaunchKernelGGL(xform_border, dim3(456), dim3(256), 0, stream, xTp);
    hipLaunchKernelGGL(xform_w, dim3(9 * CO * CI / 256), dim3(256), 0, stream, w, wT);
    hipLaunchKernelGGL(gemm_conv, dim3(392), dim3(512), 0, stream,
                       xTp, wT, b, out);
}